// Round 11
// baseline (608.289 us; speedup 1.0000x reference)
//
#include <hip/hip_runtime.h>
#include <hip/hip_fp16.h>
#include <math.h>

#define EPS 1e-5f
#define N_GRAPHS 128
#define CHUNK 8   // nodes per wave in agg (register-resident accumulators)

typedef __attribute__((ext_vector_type(8))) short s8v;
typedef __attribute__((ext_vector_type(4))) float f4v;

__device__ __forceinline__ float sigmoidf_(float x) {
    return __fdividef(1.0f, 1.0f + __expf(-x));
}

__device__ __forceinline__ short bf16rne(float f) {
    unsigned u = __builtin_bit_cast(unsigned, f);
    unsigned r = (u + 0x7FFFu + ((u >> 16) & 1u)) >> 16;
    return (short)r;
}
__device__ __forceinline__ float bf16tof(short h) {
    unsigned u = ((unsigned)(unsigned short)h) << 16;
    return __builtin_bit_cast(float, u);
}

// ---------------------------------------------------------------------------
// Fused prep: block-range partition.
//  [0,256):  (dst,bucket) histogram + per-edge rank capture (pos2_)
//  [256,320): fuse_w layer0 (K=128)   [320,384): fuse_w layer1 (K=64)
//  [384,400): per-graph counts
// bucket(src) = src >> shift (<=16 buckets; ~2MB QV slice per bucket =>
// XCD-L2-resident during agg's bucket-major passes).
// ---------------------------------------------------------------------------
__device__ __forceinline__ void fuse_w_body(
    int b0, int blk, int tid,
    const float* __restrict__ Wk, const float* __restrict__ bk,
    const float* __restrict__ Wq, const float* __restrict__ bq,
    const float* __restrict__ Wv, const float* __restrict__ bv,
    const float* __restrict__ Ws, const float* __restrict__ cbv,
    short* __restrict__ BTh, short* __restrict__ BTl,
    float* __restrict__ bf, int K)
{
    int t = (blk - b0) * 256 + tid;
    int total = K * 256;
    for (int i = t; i < total; i += 64 * 256) {
        int k = i >> 8, c = i & 255;
        const float* W;
        int cc;
        if (c < 128) { cc = c >> 1; W = (c & 1) ? Ws : Wk; }
        else { int j = c - 128; cc = j >> 1; W = (j & 1) ? Wv : Wq; }
        float wv = W[k * 64 + cc];
        short h = bf16rne(wv);
        short l = bf16rne(wv - bf16tof(h));
        BTh[(size_t)c * K + k] = h;
        BTl[(size_t)c * K + k] = l;
    }
    if (t < 256) {
        int c = t;
        const float* b;
        int cc;
        if (c < 128) { cc = c >> 1; b = (c & 1) ? cbv : bk; }
        else { int j = c - 128; cc = j >> 1; b = (j & 1) ? bv : bq; }
        bf[t] = b[cc];
    }
}

__global__ __launch_bounds__(256) void prep_kernel(
    const int* __restrict__ ei, int* __restrict__ deg2,
    int* __restrict__ pos2_, int E, int shift,
    const int* __restrict__ batch, float* __restrict__ counts, int N,
    const float* __restrict__ Wk0, const float* __restrict__ bk0,
    const float* __restrict__ Wq0, const float* __restrict__ bq0,
    const float* __restrict__ Wv0, const float* __restrict__ bv0,
    const float* __restrict__ Ws0, const float* __restrict__ cb0,
    short* __restrict__ BT0h, short* __restrict__ BT0l, float* __restrict__ bf0,
    const float* __restrict__ Wk1, const float* __restrict__ bk1,
    const float* __restrict__ Wq1, const float* __restrict__ bq1,
    const float* __restrict__ Wv1, const float* __restrict__ bv1,
    const float* __restrict__ Ws1, const float* __restrict__ cb1,
    short* __restrict__ BT1h, short* __restrict__ BT1l, float* __restrict__ bf1)
{
    const int blk = blockIdx.x;
    const int tid = threadIdx.x;
    if (blk < 256) {
        int t = blk * 256 + tid;
        for (int e = t; e < E; e += 256 * 256) {
            int s = ei[e];
            int d = ei[E + e];
            pos2_[e] = atomicAdd(&deg2[(d << 4) + (s >> shift)], 1);
        }
    } else if (blk < 320) {
        fuse_w_body(256, blk, tid, Wk0, bk0, Wq0, bq0, Wv0, bv0, Ws0, cb0,
                    BT0h, BT0l, bf0, 128);
    } else if (blk < 384) {
        fuse_w_body(320, blk, tid, Wk1, bk1, Wq1, bq1, Wv1, bv1, Ws1, cb1,
                    BT1h, BT1l, bf1, 64);
    } else {
        const int t = (blk - 384) * 256 + tid;
        const int T = 16 * 256;
        const int chunk = (N + T - 1) / T;
        const int a = t * chunk;
        const int b = min(N, a + chunk);
        int cur = -1;
        float c = 0.0f;
        for (int n = a; n < b; ++n) {
            int gi = batch[n];
            if (gi != cur) {
                if (cur >= 0) atomicAdd(&counts[cur], c);
                cur = gi;
                c = 0.0f;
            }
            c += 1.0f;
        }
        if (cur >= 0) atomicAdd(&counts[cur], c);
    }
}

// ---------------------------------------------------------------------------
// Projection (R5 configuration — best measured; persistence/pipelining
// variants A/B'd neutral-to-negative in R6/R8/R10).
// ---------------------------------------------------------------------------
template <int K, bool AFF>
__global__ __launch_bounds__(256) void proj_mfma_kernel(
    const float* __restrict__ X,
    const short* __restrict__ BTh, const short* __restrict__ BTl,
    const float* __restrict__ bf,
    const float* __restrict__ stats, const float* __restrict__ g,
    const float* __restrict__ be, float invN,
    unsigned* __restrict__ KS, unsigned* __restrict__ QV, int N)
{
    __shared__ __attribute__((aligned(16))) short Ah_s[64 * 40];
    __shared__ __attribute__((aligned(16))) short Al_s[64 * 40];
    const int tid = threadIdx.x;
    const int lane = tid & 63;
    const int w = tid >> 6;
    const int n0 = blockIdx.x * 64;
    const int m = lane & 15;
    const int kg = lane >> 4;
    const int srow = tid >> 2;
    const int skq = (tid & 3) * 8;

    f4v acc[4][4];
#pragma unroll
    for (int rb = 0; rb < 4; ++rb)
#pragma unroll
        for (int cc = 0; cc < 4; ++cc) {
            acc[rb][cc][0] = 0.0f; acc[rb][cc][1] = 0.0f;
            acc[rb][cc][2] = 0.0f; acc[rb][cc][3] = 0.0f;
        }

    for (int k0 = 0; k0 < K; k0 += 32) {
        float4 x0 = make_float4(0.f, 0.f, 0.f, 0.f);
        float4 x1 = make_float4(0.f, 0.f, 0.f, 0.f);
        const int row = n0 + srow;
        if (row < N) {
            x0 = *(const float4*)&X[(size_t)row * K + k0 + skq];
            x1 = *(const float4*)&X[(size_t)row * K + k0 + skq + 4];
        }
        s8v Bh[4], Bl[4];
#pragma unroll
        for (int cc = 0; cc < 4; ++cc) {
            const int colb = (w * 4 + cc) * 16 + m;
            const size_t off = (size_t)colb * K + k0 + kg * 8;
            Bh[cc] = *(const s8v*)&BTh[off];
            Bl[cc] = *(const s8v*)&BTl[off];
        }
        __syncthreads();
        {
            float xv[8] = {x0.x, x0.y, x0.z, x0.w, x1.x, x1.y, x1.z, x1.w};
            if constexpr (AFF) {
#pragma unroll
                for (int i = 0; i < 8; ++i) {
                    int c = k0 + skq + i;
                    float mm = stats[c] * invN;
                    float vv = stats[64 + c] * invN - mm * mm;
                    float rs = rsqrtf(vv + EPS) * g[c];
                    xv[i] = fmaf(xv[i], rs, be[c] - mm * rs);
                }
            }
            s8v vh, vl;
#pragma unroll
            for (int i = 0; i < 8; ++i) {
                short h = bf16rne(xv[i]);
                vh[i] = h;
                vl[i] = bf16rne(xv[i] - bf16tof(h));
            }
            *(s8v*)&Ah_s[srow * 40 + skq] = vh;
            *(s8v*)&Al_s[srow * 40 + skq] = vl;
        }
        __syncthreads();
#pragma unroll
        for (int rb = 0; rb < 4; ++rb) {
            const int aoff = (rb * 16 + m) * 40 + kg * 8;
            s8v Ah = *(const s8v*)&Ah_s[aoff];
            s8v Al = *(const s8v*)&Al_s[aoff];
#pragma unroll
            for (int cc = 0; cc < 4; ++cc) {
                acc[rb][cc] = __builtin_amdgcn_mfma_f32_16x16x32_bf16(
                    Ah, Bh[cc], acc[rb][cc], 0, 0, 0);
                acc[rb][cc] = __builtin_amdgcn_mfma_f32_16x16x32_bf16(
                    Ah, Bl[cc], acc[rb][cc], 0, 0, 0);
                acc[rb][cc] = __builtin_amdgcn_mfma_f32_16x16x32_bf16(
                    Al, Bh[cc], acc[rb][cc], 0, 0, 0);
            }
        }
    }

    unsigned* __restrict__ dst = (w < 2) ? KS : QV;
    const int cbase = (w < 2) ? 0 : 128;
#pragma unroll
    for (int rb = 0; rb < 4; ++rb) {
#pragma unroll
        for (int cc = 0; cc < 4; ++cc) {
            const int colb = (w * 4 + cc) * 16 + m;
            const float bias = bf[colb];
#pragma unroll
            for (int j = 0; j < 4; ++j) {
                const int row = n0 + rb * 16 + kg * 4 + j;
                float val = acc[rb][cc][j] + bias;
                float pv = __shfl_xor(val, 1);
                if (!(lane & 1) && row < N) {
                    __half2 h2 = __floats2half2_rn(val, pv);
                    dst[(size_t)row * 64 + ((colb - cbase) >> 1)] =
                        *reinterpret_cast<unsigned*>(&h2);
                }
            }
        }
    }
}

// ---------------------------------------------------------------------------
// CSR scans. scan1 sums the 16 per-node bucket bins; scan23 as before;
// scan4 builds per-node per-bucket offsets (off2) from rowptr + deg2.
// ---------------------------------------------------------------------------
__global__ __launch_bounds__(256) void scan1_kernel(
    const int* __restrict__ deg2, int* __restrict__ rp1loc,
    int* __restrict__ psum, int N)
{
    __shared__ int s[256];
    const int b = blockIdx.x;
    const int base = b * 1024;
    const int t = threadIdx.x;
    int v[4], sum = 0;
#pragma unroll
    for (int i = 0; i < 4; ++i) {
        int idx = base + t * 4 + i;
        int s16 = 0;
        if (idx < N) {
            const int4* p = (const int4*)&deg2[(size_t)idx << 4];
#pragma unroll
            for (int j = 0; j < 4; ++j) {
                int4 q = p[j];
                s16 += q.x + q.y + q.z + q.w;
            }
        }
        v[i] = s16;
        sum += s16;
    }
    s[t] = sum;
    __syncthreads();
    for (int off = 1; off < 256; off <<= 1) {
        int x = (t >= off) ? s[t - off] : 0;
        __syncthreads();
        s[t] += x;
        __syncthreads();
    }
    int run = s[t] - sum;
#pragma unroll
    for (int i = 0; i < 4; ++i) {
        run += v[i];
        int idx = base + t * 4 + i;
        if (idx < N) rp1loc[idx] = run;
    }
    if (t == 255) psum[b] = s[255];
}

__global__ __launch_bounds__(256) void scan23_kernel(
    const int* __restrict__ rp1loc, const int* __restrict__ psum,
    int* __restrict__ rowptr, int N, int NBLK)
{
    __shared__ int s[256];
    __shared__ int ex[256];
    const int t = threadIdx.x;
    int c = (t < NBLK) ? psum[t] : 0;
    s[t] = c;
    __syncthreads();
    for (int off = 1; off < 256; off <<= 1) {
        int x = (t >= off) ? s[t - off] : 0;
        __syncthreads();
        s[t] += x;
        __syncthreads();
    }
    ex[t] = s[t] - c;
    __syncthreads();
    int idx = blockIdx.x * 256 + t;
    int T = gridDim.x * 256;
    for (int i = idx; i < N; i += T) {
        rowptr[i + 1] = rp1loc[i] + ex[i >> 10];
    }
    if (idx == 0) rowptr[0] = 0;
}

__global__ __launch_bounds__(256) void scan4_kernel(
    const int* __restrict__ rowptr, const int* __restrict__ deg2,
    int* __restrict__ off2, int N)
{
    int t = blockIdx.x * 256 + threadIdx.x;
    int T = gridDim.x * 256;
    for (int n = t; n < N; n += T) {
        int run = rowptr[n];
#pragma unroll
        for (int b = 0; b < 16; ++b) {
            off2[((size_t)n << 4) + b] = run;
            run += deg2[((size_t)n << 4) + b];
        }
    }
}

// scatter: bucket-sorted within each dst; col carries src | bucket<<24.
__global__ __launch_bounds__(256) void scatter_kernel(
    const int* __restrict__ ei, const int* __restrict__ off2,
    const int* __restrict__ pos2_, int* __restrict__ col, int E, int shift)
{
    int t = blockIdx.x * 256 + threadIdx.x;
    int T = gridDim.x * 256;
    for (int e = t; e < E; e += T) {
        int s = ei[e];
        int d = ei[E + e];
        int bk = s >> shift;
        col[off2[((size_t)d << 4) + bk] + pos2_[e]] = s | (bk << 24);
    }
}

// ---------------------------------------------------------------------------
// Aggregation v9: bucket-major gathers. Each wave owns CHUNK=8 nodes with
// register-resident accumulators; edges are bucket-sorted (tags in col high
// bits), so ascending bucket passes walk each node's list exactly once with
// monotone cursors. All waves process bucket b's ~2MB QV slice together ->
// gathers hit XCD L2 (~200cy) instead of HBM (~900cy).
// ---------------------------------------------------------------------------
__global__ __launch_bounds__(256) void agg_kernel(
    const int* __restrict__ rowptr, const int* __restrict__ col,
    const unsigned* __restrict__ KS, const unsigned* __restrict__ QV,
    const int* __restrict__ batch,
    float* __restrict__ H, float* __restrict__ stats,
    float* __restrict__ gsumy, int N, int NB)
{
    const int tid = threadIdx.x;
    const int lane = tid & 63;
    const int wid = __builtin_amdgcn_readfirstlane(
        (int)((blockIdx.x * blockDim.x + tid) >> 6));
    const int nA = wid * CHUNK;
    const int nB_ = min(N, nA + CHUNK);
    const int cnt = nB_ - nA;
    const float L2E = 1.44269504f;

    float acc[CHUNK], nkl[CHUNK];
    int ec[CHUNK], er[CHUNK];

#pragma unroll
    for (int i = 0; i < CHUNK; ++i) {
        int n = nA + i;
        if (i < cnt) {
            ec[i] = __builtin_amdgcn_readfirstlane(rowptr[n]);
            er[i] = __builtin_amdgcn_readfirstlane(rowptr[n + 1]);
            unsigned ks = KS[(size_t)n * 64 + lane];
            float2 kf = __half22float2(*reinterpret_cast<__half2*>(&ks));
            acc[i] = kf.y;
            nkl[i] = kf.x * (-L2E);
        } else {
            ec[i] = 0; er[i] = 0; acc[i] = 0.0f; nkl[i] = 0.0f;
        }
    }

    for (int b = 0; b < NB; ++b) {
#pragma unroll
        for (int i = 0; i < CHUNK; ++i) {
            while (ec[i] < er[i]) {
                int c = __builtin_amdgcn_readfirstlane(col[ec[i]]);
                if ((c >> 24) != b) break;   // buckets ascend within a node
                int s = c & 0xFFFFFF;
                unsigned u = QV[((size_t)s << 6) + lane];
                float2 f = __half22float2(*reinterpret_cast<__half2*>(&u));
                float ex = __builtin_amdgcn_exp2f(fmaf(f.x, -L2E, nkl[i]));
                acc[i] = fmaf(__builtin_amdgcn_rcpf(1.0f + ex), f.y, acc[i]);
                ec[i]++;
            }
        }
    }

    float st1 = 0.0f, st2 = 0.0f, gacc = 0.0f;
    int cur = -1;
#pragma unroll
    for (int i = 0; i < CHUNK; ++i) {
        if (i < cnt) {
            int n = nA + i;
            float y = __builtin_amdgcn_rcpf(
                1.0f + __builtin_amdgcn_exp2f(acc[i] * (-L2E)));
            H[(size_t)n * 64 + lane] = y;
            st1 += y;
            st2 += y * y;
            int gi = __builtin_amdgcn_readfirstlane(batch[n]);
            if (gi != cur) {
                if (cur >= 0) atomicAdd(&gsumy[cur * 64 + lane], gacc);
                gacc = 0.0f;
                cur = gi;
            }
            gacc += y;
        }
    }
    if (cur >= 0) atomicAdd(&gsumy[cur * 64 + lane], gacc);

    __shared__ float red1[4][64], red2[4][64];
    const int w = tid >> 6;
    red1[w][lane] = st1;
    red2[w][lane] = st2;
    __syncthreads();
    if (tid < 64) {
        float a = red1[0][lane] + red1[1][lane] + red1[2][lane] + red1[3][lane];
        float c = red2[0][lane] + red2[1][lane] + red2[2][lane] + red2[3][lane];
        atomicAdd(&stats[lane], a);
        atomicAdd(&stats[64 + lane], c);
    }
}

// ---------------------------------------------------------------------------
// Head kernels (unchanged).
// ---------------------------------------------------------------------------
__global__ __launch_bounds__(128) void head1_kernel(
    const float* __restrict__ gsumy0, const float* __restrict__ gsumy1,
    const float* __restrict__ counts,
    const float* __restrict__ stats0, const float* __restrict__ stats1,
    const float* __restrict__ g0, const float* __restrict__ be0,
    const float* __restrict__ g1, const float* __restrict__ be1,
    const float* __restrict__ Wh0, const float* __restrict__ bh0,
    float* __restrict__ t0, float* __restrict__ hstat0, float invN)
{
    const int gr = blockIdx.x;
    const int o = threadIdx.x;
    __shared__ float feat[256];

    const float* st = (o < 64) ? stats0 : stats1;
    const float* gg = (o < 64) ? g0 : g1;
    const float* bb = (o < 64) ? be0 : be1;
    const float* gs = (o < 64) ? gsumy0 : gsumy1;
    int c = o & 63;
    float m = st[c] * invN;
    float var = st[64 + c] * invN - m * m;
    float rs = rsqrtf(var + EPS) * gg[c];
    float off = bb[c] - m * rs;
    float cnt = counts[gr];
    float sv = rs * gs[gr * 64 + c] + cnt * off;
    float inv = __fdividef(1.0f, fmaxf(cnt, 1.0f));
    feat[o] = sv * inv;
    feat[128 + o] = sv;
    __syncthreads();

    float acc = bh0[o];
    for (int j = 0; j < 256; ++j) acc = fmaf(feat[j], Wh0[j * 128 + o], acc);
    float y = sigmoidf_(acc);
    t0[gr * 128 + o] = y;
    atomicAdd(&hstat0[o], y);
    atomicAdd(&hstat0[128 + o], y * y);
}

__global__ __launch_bounds__(64) void head2_kernel(
    const float* __restrict__ t0, const float* __restrict__ hstat0,
    const float* __restrict__ gh0, const float* __restrict__ beh0,
    const float* __restrict__ Wh1, const float* __restrict__ bh1,
    float* __restrict__ t1, float* __restrict__ hstat1)
{
    const int gr = blockIdx.x;
    const int o = threadIdx.x;
    __shared__ float bn0[128];
    const float invG = 1.0f / (float)N_GRAPHS;
    for (int j = o; j < 128; j += 64) {
        float m = hstat0[j] * invG;
        float v = hstat0[128 + j] * invG - m * m;
        bn0[j] = (t0[gr * 128 + j] - m) * rsqrtf(v + EPS) * gh0[j] + beh0[j];
    }
    __syncthreads();
    float acc = bh1[o];
    for (int j = 0; j < 128; ++j) acc = fmaf(bn0[j], Wh1[j * 64 + o], acc);
    float y = sigmoidf_(acc);
    t1[gr * 64 + o] = y;
    atomicAdd(&hstat1[o], y);
    atomicAdd(&hstat1[64 + o], y * y);
}

__global__ __launch_bounds__(64) void head3_kernel(
    const float* __restrict__ t1, const float* __restrict__ hstat1,
    const float* __restrict__ gh1, const float* __restrict__ beh1,
    const float* __restrict__ Wc, const float* __restrict__ bc,
    float* __restrict__ out)
{
    const int gr = blockIdx.x;
    const int o = threadIdx.x;
    const float invG = 1.0f / (float)N_GRAPHS;
    float m = hstat1[o] * invG;
    float v = hstat1[64 + o] * invG - m * m;
    float b = (t1[gr * 64 + o] - m) * rsqrtf(v + EPS) * gh1[o] + beh1[o];
    float p0 = b * Wc[o * 2];
    float p1 = b * Wc[o * 2 + 1];
#pragma unroll
    for (int off = 32; off > 0; off >>= 1) {
        p0 += __shfl_down(p0, off);
        p1 += __shfl_down(p1, off);
    }
    if (o == 0) {
        out[gr * 2] = p0 + bc[0];
        out[gr * 2 + 1] = p1 + bc[1];
    }
}

// ---------------------------------------------------------------------------
extern "C" void kernel_launch(void* const* d_in, const int* in_sizes, int n_in,
                              void* d_out, int out_size, void* d_ws, size_t ws_size,
                              hipStream_t stream)
{
    const float* x     = (const float*)d_in[0];
    const int*   ei    = (const int*)d_in[1];
    const int*   batch = (const int*)d_in[2];
    const int N = in_sizes[2];
    const int E = in_sizes[1] / 2;
    const int NCHUNK = (N + 1023) / 1024;

    const float *Wk0 = (const float*)d_in[3],  *bk0 = (const float*)d_in[4];
    const float *Wq0 = (const float*)d_in[5],  *bq0 = (const float*)d_in[6];
    const float *Wv0 = (const float*)d_in[7],  *bv0 = (const float*)d_in[8];
    const float *Ws0 = (const float*)d_in[9],  *cb0 = (const float*)d_in[10];
    const float *g0  = (const float*)d_in[11], *be0 = (const float*)d_in[12];
    const float *Wk1 = (const float*)d_in[13], *bk1 = (const float*)d_in[14];
    const float *Wq1 = (const float*)d_in[15], *bq1 = (const float*)d_in[16];
    const float *Wv1 = (const float*)d_in[17], *bv1 = (const float*)d_in[18];
    const float *Ws1 = (const float*)d_in[19], *cb1 = (const float*)d_in[20];
    const float *g1  = (const float*)d_in[21], *be1 = (const float*)d_in[22];
    const float *Wh0 = (const float*)d_in[23], *bh0 = (const float*)d_in[24];
    const float *gh0 = (const float*)d_in[25], *beh0 = (const float*)d_in[26];
    const float *Wh1 = (const float*)d_in[27], *bh1 = (const float*)d_in[28];
    const float *gh1 = (const float*)d_in[29], *beh1 = (const float*)d_in[30];
    const float *Wc  = (const float*)d_in[31], *bc  = (const float*)d_in[32];

    float*    ws = (float*)d_ws;
    unsigned* KS = (unsigned*)ws;                      // N*64 packed fp16 k|s
    unsigned* QV = KS + (size_t)N * 64;                // N*64 packed fp16 q|v
    float*    H  = (float*)(QV + (size_t)N * 64);      // N*64 fp32 (raw y)
    int*   col     = (int*)(H + (size_t)N * 64);       // E
    int*   rowptr  = col + E;             // N+1
    int*   rp1loc  = rowptr + N + 1;      // N
    int*   cursor  = rp1loc + N;          // N (unused; kept for layout)
    int*   psum    = cursor + N;          // 256
    uintptr_t pAl = ((uintptr_t)(psum + 256) + 63) & ~(uintptr_t)63;
    short* BT0h = (short*)pAl;            // 256*128 bf16 hi
    short* BT0l = BT0h + 256 * 128;       // 256*128 bf16 lo
    float* bf0  = (float*)(BT0l + 256 * 128);  // 256
    short* BT1h = (short*)(bf0 + 256);    // 256*64 bf16 hi
    short* BT1l = BT1h + 256 * 64;        // 256*64 bf16 lo
    float* bf1  = (float*)(BT1l + 256 * 64);   // 256
    int*   deg     = (int*)(bf1 + 256);   // N (unused; kept for layout)
    float* gsumy0 = (float*)(deg + N);    // 128*64
    float* gsumy1 = gsumy0 + 128 * 64;    // 128*64
    float* counts = gsumy1 + 128 * 64;    // 128
    float* stats0 = counts + 128;         // 128
    float* stats1 = stats0 + 128;         // 128
    float* hstat0 = stats1 + 128;         // 256
    float* hstat1 = hstat0 + 256;         // 128
    size_t zbytes = (size_t)N * sizeof(int) +
                    (size_t)(128 * 64 * 2 + 128 * 3 + 256 + 128) * sizeof(float);
    float* t0 = hstat1 + 128;             // 128*128
    float* t1 = t0 + 128 * 128;           // 128*64

    // Transient aliases (all dead before proj0/agg0 touch their hosts):
    //   pos2_ -> KS region (E ints <= N*64 u32)
    //   deg2, off2 -> H region (N*16 ints each; 2*N*64B <= N*256B)
    int* pos2_ = (int*)KS;
    int* deg2  = (int*)H;
    int* off2  = deg2 + (size_t)N * 16;

    // bucket shift: <=16 buckets over N rows (~2MB QV slice per bucket)
    int shift = 13;
    while ((((N - 1) >> shift) + 1) > 16) ++shift;
    const int NB = ((N - 1) >> shift) + 1;

    hipMemsetAsync(deg, 0, zbytes, stream);
    hipMemsetAsync(deg2, 0, (size_t)N * 16 * sizeof(int), stream);

    // ---- fused prep ((dst,bucket) histogram + counts + weights) ----
    prep_kernel<<<400, 256, 0, stream>>>(
        ei, deg2, pos2_, E, shift, batch, counts, N,
        Wk0, bk0, Wq0, bq0, Wv0, bv0, Ws0, cb0, BT0h, BT0l, bf0,
        Wk1, bk1, Wq1, bq1, Wv1, bv1, Ws1, cb1, BT1h, BT1l, bf1);
    scan1_kernel<<<NCHUNK, 256, 0, stream>>>(deg2, rp1loc, psum, N);
    scan23_kernel<<<256, 256, 0, stream>>>(rp1loc, psum, rowptr, N, NCHUNK);
    scan4_kernel<<<256, 256, 0, stream>>>(rowptr, deg2, off2, N);
    scatter_kernel<<<512, 256, 0, stream>>>(ei, off2, pos2_, col, E, shift);

    const float invN = 1.0f / (float)N;
    const int projBlocks = (N + 63) / 64;
    const int aggBlocks = (N + CHUNK * 4 - 1) / (CHUNK * 4);

    // ---- layer 0 ----
    proj_mfma_kernel<128, false><<<projBlocks, 256, 0, stream>>>(
        x, BT0h, BT0l, bf0, nullptr, nullptr, nullptr, invN, KS, QV, N);
    agg_kernel<<<aggBlocks, 256, 0, stream>>>(rowptr, col, KS, QV, batch,
                                              H, stats0, gsumy0, N, NB);

    // ---- layer 1 (BN affine computed in-kernel from stats0) ----
    proj_mfma_kernel<64, true><<<projBlocks, 256, 0, stream>>>(
        H, BT1h, BT1l, bf1, stats0, g0, be0, invN, KS, QV, N);
    agg_kernel<<<aggBlocks, 256, 0, stream>>>(rowptr, col, KS, QV, batch,
                                              H, stats1, gsumy1, N, NB);

    // ---- head ----
    head1_kernel<<<128, 128, 0, stream>>>(gsumy0, gsumy1, counts,
                                          stats0, stats1, g0, be0, g1, be1,
                                          Wh0, bh0, t0, hstat0, invN);
    head2_kernel<<<128, 64, 0, stream>>>(t0, hstat0, gh0, beh0, Wh1, bh1, t1, hstat1);
    head3_kernel<<<128, 64, 0, stream>>>(t1, hstat1, gh1, beh1, Wc, bc, (float*)d_out);
}

// Round 12
// 483.917 us; speedup vs baseline: 1.2570x; 1.2570x over previous
//
#include <hip/hip_runtime.h>
#include <hip/hip_fp16.h>
#include <math.h>

#define EPS 1e-5f
#define N_GRAPHS 128

typedef __attribute__((ext_vector_type(8))) short s8v;
typedef __attribute__((ext_vector_type(4))) float f4v;

__device__ __forceinline__ float sigmoidf_(float x) {
    return __fdividef(1.0f, 1.0f + __expf(-x));
}

__device__ __forceinline__ short bf16rne(float f) {
    unsigned u = __builtin_bit_cast(unsigned, f);
    unsigned r = (u + 0x7FFFu + ((u >> 16) & 1u)) >> 16;
    return (short)r;
}
__device__ __forceinline__ float bf16tof(short h) {
    unsigned u = ((unsigned)(unsigned short)h) << 16;
    return __builtin_bit_cast(float, u);
}

// ---------------------------------------------------------------------------
// Fused prep: block-range partition.
//  [0,256):  deg histogram + per-edge slot capture (pos_)
//  [256,320): fuse_w layer0 (K=128)   [320,384): fuse_w layer1 (K=64)
//  [384,400): per-graph counts
// Fused weight layout (cols): [0,128) = interleaved (Wk,Ws) pairs,
// [128,256) = interleaved (Wq,Wv) pairs. Transposed to [col][k], SPLIT into
// hi/lo bf16 (3-product split-bf16 MFMA ~ fp32 accuracy).
// ---------------------------------------------------------------------------
__device__ __forceinline__ void fuse_w_body(
    int b0, int blk, int tid,
    const float* __restrict__ Wk, const float* __restrict__ bk,
    const float* __restrict__ Wq, const float* __restrict__ bq,
    const float* __restrict__ Wv, const float* __restrict__ bv,
    const float* __restrict__ Ws, const float* __restrict__ cbv,
    short* __restrict__ BTh, short* __restrict__ BTl,
    float* __restrict__ bf, int K)
{
    int t = (blk - b0) * 256 + tid;
    int total = K * 256;
    for (int i = t; i < total; i += 64 * 256) {
        int k = i >> 8, c = i & 255;
        const float* W;
        int cc;
        if (c < 128) { cc = c >> 1; W = (c & 1) ? Ws : Wk; }
        else { int j = c - 128; cc = j >> 1; W = (j & 1) ? Wv : Wq; }
        float wv = W[k * 64 + cc];
        short h = bf16rne(wv);
        short l = bf16rne(wv - bf16tof(h));
        BTh[(size_t)c * K + k] = h;
        BTl[(size_t)c * K + k] = l;
    }
    if (t < 256) {
        int c = t;
        const float* b;
        int cc;
        if (c < 128) { cc = c >> 1; b = (c & 1) ? cbv : bk; }
        else { int j = c - 128; cc = j >> 1; b = (j & 1) ? bv : bq; }
        bf[t] = b[cc];
    }
}

__global__ __launch_bounds__(256) void prep_kernel(
    const int* __restrict__ ei, int* __restrict__ deg,
    int* __restrict__ pos_, int E,
    const int* __restrict__ batch, float* __restrict__ counts, int N,
    const float* __restrict__ Wk0, const float* __restrict__ bk0,
    const float* __restrict__ Wq0, const float* __restrict__ bq0,
    const float* __restrict__ Wv0, const float* __restrict__ bv0,
    const float* __restrict__ Ws0, const float* __restrict__ cb0,
    short* __restrict__ BT0h, short* __restrict__ BT0l, float* __restrict__ bf0,
    const float* __restrict__ Wk1, const float* __restrict__ bk1,
    const float* __restrict__ Wq1, const float* __restrict__ bq1,
    const float* __restrict__ Wv1, const float* __restrict__ bv1,
    const float* __restrict__ Ws1, const float* __restrict__ cb1,
    short* __restrict__ BT1h, short* __restrict__ BT1l, float* __restrict__ bf1)
{
    const int blk = blockIdx.x;
    const int tid = threadIdx.x;
    if (blk < 256) {
        int t = blk * 256 + tid;
        for (int e = t; e < E; e += 256 * 256) {
            pos_[e] = atomicAdd(&deg[ei[E + e]], 1);
        }
    } else if (blk < 320) {
        fuse_w_body(256, blk, tid, Wk0, bk0, Wq0, bq0, Wv0, bv0, Ws0, cb0,
                    BT0h, BT0l, bf0, 128);
    } else if (blk < 384) {
        fuse_w_body(320, blk, tid, Wk1, bk1, Wq1, bq1, Wv1, bv1, Ws1, cb1,
                    BT1h, BT1l, bf1, 64);
    } else {
        const int t = (blk - 384) * 256 + tid;
        const int T = 16 * 256;
        const int chunk = (N + T - 1) / T;
        const int a = t * chunk;
        const int b = min(N, a + chunk);
        int cur = -1;
        float c = 0.0f;
        for (int n = a; n < b; ++n) {
            int gi = batch[n];
            if (gi != cur) {
                if (cur >= 0) atomicAdd(&counts[cur], c);
                cur = gi;
                c = 0.0f;
            }
            c += 1.0f;
        }
        if (cur >= 0) atomicAdd(&counts[cur], c);
    }
}

// ---------------------------------------------------------------------------
// Projection: split-bf16 MFMA GEMM (AhBh + AhBl + AlBh, fp32 accumulate).
// Tile M=64 x N=256 fused cols; 4 waves each own 64 cols x 64 rows.
// Per K-step: X-loads and B-loads issued together before ONE barrier drain.
// Output: all fp16x2-packed pairs — w<2 -> KS (k,s), w>=2 -> QV (q,v).
// ---------------------------------------------------------------------------
template <int K, bool AFF>
__global__ __launch_bounds__(256) void proj_mfma_kernel(
    const float* __restrict__ X,
    const short* __restrict__ BTh, const short* __restrict__ BTl,
    const float* __restrict__ bf,
    const float* __restrict__ stats, const float* __restrict__ g,
    const float* __restrict__ be, float invN,
    unsigned* __restrict__ KS, unsigned* __restrict__ QV, int N)
{
    __shared__ __attribute__((aligned(16))) short Ah_s[64 * 40];
    __shared__ __attribute__((aligned(16))) short Al_s[64 * 40];
    const int tid = threadIdx.x;
    const int lane = tid & 63;
    const int w = tid >> 6;
    const int n0 = blockIdx.x * 64;
    const int m = lane & 15;
    const int kg = lane >> 4;
    const int srow = tid >> 2;
    const int skq = (tid & 3) * 8;

    f4v acc[4][4];
#pragma unroll
    for (int rb = 0; rb < 4; ++rb)
#pragma unroll
        for (int cc = 0; cc < 4; ++cc) {
            acc[rb][cc][0] = 0.0f; acc[rb][cc][1] = 0.0f;
            acc[rb][cc][2] = 0.0f; acc[rb][cc][3] = 0.0f;
        }

    for (int k0 = 0; k0 < K; k0 += 32) {
        float4 x0 = make_float4(0.f, 0.f, 0.f, 0.f);
        float4 x1 = make_float4(0.f, 0.f, 0.f, 0.f);
        const int row = n0 + srow;
        if (row < N) {
            x0 = *(const float4*)&X[(size_t)row * K + k0 + skq];
            x1 = *(const float4*)&X[(size_t)row * K + k0 + skq + 4];
        }
        s8v Bh[4], Bl[4];
#pragma unroll
        for (int cc = 0; cc < 4; ++cc) {
            const int colb = (w * 4 + cc) * 16 + m;
            const size_t off = (size_t)colb * K + k0 + kg * 8;
            Bh[cc] = *(const s8v*)&BTh[off];
            Bl[cc] = *(const s8v*)&BTl[off];
        }
        __syncthreads();
        {
            float xv[8] = {x0.x, x0.y, x0.z, x0.w, x1.x, x1.y, x1.z, x1.w};
            if constexpr (AFF) {
#pragma unroll
                for (int i = 0; i < 8; ++i) {
                    int c = k0 + skq + i;
                    float mm = stats[c] * invN;
                    float vv = stats[64 + c] * invN - mm * mm;
                    float rs = rsqrtf(vv + EPS) * g[c];
                    xv[i] = fmaf(xv[i], rs, be[c] - mm * rs);
                }
            }
            s8v vh, vl;
#pragma unroll
            for (int i = 0; i < 8; ++i) {
                short h = bf16rne(xv[i]);
                vh[i] = h;
                vl[i] = bf16rne(xv[i] - bf16tof(h));
            }
            *(s8v*)&Ah_s[srow * 40 + skq] = vh;
            *(s8v*)&Al_s[srow * 40 + skq] = vl;
        }
        __syncthreads();
#pragma unroll
        for (int rb = 0; rb < 4; ++rb) {
            const int aoff = (rb * 16 + m) * 40 + kg * 8;
            s8v Ah = *(const s8v*)&Ah_s[aoff];
            s8v Al = *(const s8v*)&Al_s[aoff];
#pragma unroll
            for (int cc = 0; cc < 4; ++cc) {
                acc[rb][cc] = __builtin_amdgcn_mfma_f32_16x16x32_bf16(
                    Ah, Bh[cc], acc[rb][cc], 0, 0, 0);
                acc[rb][cc] = __builtin_amdgcn_mfma_f32_16x16x32_bf16(
                    Ah, Bl[cc], acc[rb][cc], 0, 0, 0);
                acc[rb][cc] = __builtin_amdgcn_mfma_f32_16x16x32_bf16(
                    Al, Bh[cc], acc[rb][cc], 0, 0, 0);
            }
        }
    }

    // Epilogue: uniform fp16x2 pair-pack for every wave.
    unsigned* __restrict__ dst = (w < 2) ? KS : QV;
    const int cbase = (w < 2) ? 0 : 128;
#pragma unroll
    for (int rb = 0; rb < 4; ++rb) {
#pragma unroll
        for (int cc = 0; cc < 4; ++cc) {
            const int colb = (w * 4 + cc) * 16 + m;
            const float bias = bf[colb];
#pragma unroll
            for (int j = 0; j < 4; ++j) {
                const int row = n0 + rb * 16 + kg * 4 + j;
                float val = acc[rb][cc][j] + bias;
                float pv = __shfl_xor(val, 1);
                if (!(lane & 1) && row < N) {
                    __half2 h2 = __floats2half2_rn(val, pv);
                    dst[(size_t)row * 64 + ((colb - cbase) >> 1)] =
                        *reinterpret_cast<unsigned*>(&h2);
                }
            }
        }
    }
}

// ---------------------------------------------------------------------------
// CSR scans + atomic-free scatter.
// ---------------------------------------------------------------------------
__global__ __launch_bounds__(256) void scan1_kernel(
    const int* __restrict__ deg, int* __restrict__ rp1loc,
    int* __restrict__ psum, int N)
{
    __shared__ int s[256];
    const int b = blockIdx.x;
    const int base = b * 1024;
    const int t = threadIdx.x;
    int v[4], sum = 0;
#pragma unroll
    for (int i = 0; i < 4; ++i) {
        int idx = base + t * 4 + i;
        v[i] = (idx < N) ? deg[idx] : 0;
        sum += v[i];
    }
    s[t] = sum;
    __syncthreads();
    for (int off = 1; off < 256; off <<= 1) {
        int x = (t >= off) ? s[t - off] : 0;
        __syncthreads();
        s[t] += x;
        __syncthreads();
    }
    int run = s[t] - sum;
#pragma unroll
    for (int i = 0; i < 4; ++i) {
        run += v[i];
        int idx = base + t * 4 + i;
        if (idx < N) rp1loc[idx] = run;
    }
    if (t == 255) psum[b] = s[255];
}

__global__ __launch_bounds__(256) void scan2_kernel(int* __restrict__ psum, int NBLK)
{
    __shared__ int s[256];
    int t = threadIdx.x;
    int c = (t < NBLK) ? psum[t] : 0;
    s[t] = c;
    __syncthreads();
    for (int off = 1; off < 256; off <<= 1) {
        int x = (t >= off) ? s[t - off] : 0;
        __syncthreads();
        s[t] += x;
        __syncthreads();
    }
    if (t < NBLK) psum[t] = s[t] - c;
}

__global__ __launch_bounds__(256) void scan3_kernel(
    const int* __restrict__ rp1loc, const int* __restrict__ psum,
    int* __restrict__ rowptr, int N)
{
    int t = blockIdx.x * 256 + threadIdx.x;
    int T = gridDim.x * 256;
    for (int i = t; i < N; i += T) {
        rowptr[i + 1] = rp1loc[i] + psum[i >> 10];
    }
    if (t == 0) rowptr[0] = 0;
}

__global__ __launch_bounds__(256) void scatter_kernel(
    const int* __restrict__ ei, const int* __restrict__ rowptr,
    const int* __restrict__ pos_, int* __restrict__ col, int E)
{
    int t = blockIdx.x * 256 + threadIdx.x;
    int T = gridDim.x * 256;
    for (int e = t; e < E; e += T) {
        int d = ei[E + e];
        col[rowptr[d] + pos_[e]] = ei[e];
    }
}

// ---------------------------------------------------------------------------
// Aggregation: streaming edge pipeline (R5 configuration — best measured;
// MLP widening, pipelining, edge-balance, and bucketing all A/B'd
// null-to-negative; at its per-CU miss-concurrency floor ~85us).
// ---------------------------------------------------------------------------
__global__ __launch_bounds__(256) void agg_kernel(
    const int* __restrict__ rowptr, const int* __restrict__ col,
    const unsigned* __restrict__ KS, const unsigned* __restrict__ QV,
    const int* __restrict__ batch,
    float* __restrict__ H, float* __restrict__ stats,
    float* __restrict__ gsumy, int N)
{
    const int tid = threadIdx.x;
    const int lane = tid & 63;
    const int wid = __builtin_amdgcn_readfirstlane(
        (int)((blockIdx.x * blockDim.x + tid) >> 6));
    const int NW = (gridDim.x * blockDim.x) >> 6;
    const int chunk = (N + NW - 1) / NW;
    const int nA = wid * chunk;
    const int nB = min(N, nA + chunk);
    const float L2E = 1.44269504f;

    float st1 = 0.0f, st2 = 0.0f, gacc = 0.0f;
    int cur = -1;

    if (nA < nB) {
        int n = nA;
        int e = __builtin_amdgcn_readfirstlane(rowptr[nA]);
        const int eB = __builtin_amdgcn_readfirstlane(rowptr[nB]);
        int r1 = __builtin_amdgcn_readfirstlane(rowptr[nA + 1]);
        unsigned ks0 = KS[(size_t)n * 64 + lane];
        float2 kf = __half22float2(*reinterpret_cast<__half2*>(&ks0));
        float acc = kf.y;
        float nkl = kf.x * (-L2E);

        auto finishAdvance = [&]() {
            float y = __builtin_amdgcn_rcpf(
                1.0f + __builtin_amdgcn_exp2f(acc * (-L2E)));
            H[(size_t)n * 64 + lane] = y;
            st1 += y;
            st2 += y * y;
            int gi = __builtin_amdgcn_readfirstlane(batch[n]);
            if (gi != cur) {
                if (cur >= 0) atomicAdd(&gsumy[cur * 64 + lane], gacc);
                gacc = 0.0f;
                cur = gi;
            }
            gacc += y;
            ++n;
            if (n < nB) {
                r1 = __builtin_amdgcn_readfirstlane(rowptr[n + 1]);
                unsigned ks1 = KS[(size_t)n * 64 + lane];
                float2 kf1 = __half22float2(*reinterpret_cast<__half2*>(&ks1));
                acc = kf1.y;
                nkl = kf1.x * (-L2E);
            }
        };

#define RFL_(v, i) int v = __builtin_amdgcn_readfirstlane(col[e + i]);
#define GATH_(u, v) unsigned u = QV[((size_t)v << 6) + lane];
#define EDGE_(u, i)                                                          \
    {                                                                        \
        while (e + i == r1) finishAdvance();                                 \
        unsigned uu_ = u;                                                    \
        float2 f_ = __half22float2(*reinterpret_cast<__half2*>(&uu_));       \
        float ex_ = __builtin_amdgcn_exp2f(fmaf(f_.x, -L2E, nkl));           \
        acc = fmaf(__builtin_amdgcn_rcpf(1.0f + ex_), f_.y, acc);            \
    }

        while (e + 16 <= eB) {
            RFL_(sa_, 0)  RFL_(sb_, 1)  RFL_(sc_, 2)  RFL_(sd_, 3)
            RFL_(se_, 4)  RFL_(sf_, 5)  RFL_(sg_, 6)  RFL_(sh_, 7)
            RFL_(si_, 8)  RFL_(sj_, 9)  RFL_(sk_, 10) RFL_(sl_, 11)
            RFL_(sm_, 12) RFL_(sn_, 13) RFL_(so_, 14) RFL_(sp_, 15)
            GATH_(ua_, sa_) GATH_(ub_, sb_) GATH_(uc_, sc_) GATH_(ud_, sd_)
            GATH_(ue_, se_) GATH_(uf_, sf_) GATH_(ug_, sg_) GATH_(uh_, sh_)
            GATH_(ui_, si_) GATH_(uj_, sj_) GATH_(uk_, sk_) GATH_(ul_, sl_)
            GATH_(um_, sm_) GATH_(un_, sn_) GATH_(uo_, so_) GATH_(up_, sp_)
            EDGE_(ua_, 0)  EDGE_(ub_, 1)  EDGE_(uc_, 2)  EDGE_(ud_, 3)
            EDGE_(ue_, 4)  EDGE_(uf_, 5)  EDGE_(ug_, 6)  EDGE_(uh_, 7)
            EDGE_(ui_, 8)  EDGE_(uj_, 9)  EDGE_(uk_, 10) EDGE_(ul_, 11)
            EDGE_(um_, 12) EDGE_(un_, 13) EDGE_(uo_, 14) EDGE_(up_, 15)
            e += 16;
        }
        for (; e < eB; ++e) {
            while (e == r1) finishAdvance();
            int sx_ = __builtin_amdgcn_readfirstlane(col[e]);
            unsigned ux_ = QV[((size_t)sx_ << 6) + lane];
            float2 f_ = __half22float2(*reinterpret_cast<__half2*>(&ux_));
            float ex_ = __builtin_amdgcn_exp2f(fmaf(f_.x, -L2E, nkl));
            acc = fmaf(__builtin_amdgcn_rcpf(1.0f + ex_), f_.y, acc);
        }
        while (n < nB) finishAdvance();
#undef RFL_
#undef GATH_
#undef EDGE_
    }
    if (cur >= 0) atomicAdd(&gsumy[cur * 64 + lane], gacc);

    __shared__ float red1[4][64], red2[4][64];
    const int w = tid >> 6;
    red1[w][lane] = st1;
    red2[w][lane] = st2;
    __syncthreads();
    if (tid < 64) {
        float a = red1[0][lane] + red1[1][lane] + red1[2][lane] + red1[3][lane];
        float c = red2[0][lane] + red2[1][lane] + red2[2][lane] + red2[3][lane];
        atomicAdd(&stats[lane], a);
        atomicAdd(&stats[64 + lane], c);
    }
}

// ---------------------------------------------------------------------------
// Head kernels (unchanged).
// ---------------------------------------------------------------------------
__global__ __launch_bounds__(128) void head1_kernel(
    const float* __restrict__ gsumy0, const float* __restrict__ gsumy1,
    const float* __restrict__ counts,
    const float* __restrict__ stats0, const float* __restrict__ stats1,
    const float* __restrict__ g0, const float* __restrict__ be0,
    const float* __restrict__ g1, const float* __restrict__ be1,
    const float* __restrict__ Wh0, const float* __restrict__ bh0,
    float* __restrict__ t0, float* __restrict__ hstat0, float invN)
{
    const int gr = blockIdx.x;
    const int o = threadIdx.x;
    __shared__ float feat[256];

    const float* st = (o < 64) ? stats0 : stats1;
    const float* gg = (o < 64) ? g0 : g1;
    const float* bb = (o < 64) ? be0 : be1;
    const float* gs = (o < 64) ? gsumy0 : gsumy1;
    int c = o & 63;
    float m = st[c] * invN;
    float var = st[64 + c] * invN - m * m;
    float rs = rsqrtf(var + EPS) * gg[c];
    float off = bb[c] - m * rs;
    float cnt = counts[gr];
    float sv = rs * gs[gr * 64 + c] + cnt * off;
    float inv = __fdividef(1.0f, fmaxf(cnt, 1.0f));
    feat[o] = sv * inv;
    feat[128 + o] = sv;
    __syncthreads();

    float acc = bh0[o];
    for (int j = 0; j < 256; ++j) acc = fmaf(feat[j], Wh0[j * 128 + o], acc);
    float y = sigmoidf_(acc);
    t0[gr * 128 + o] = y;
    atomicAdd(&hstat0[o], y);
    atomicAdd(&hstat0[128 + o], y * y);
}

__global__ __launch_bounds__(64) void head2_kernel(
    const float* __restrict__ t0, const float* __restrict__ hstat0,
    const float* __restrict__ gh0, const float* __restrict__ beh0,
    const float* __restrict__ Wh1, const float* __restrict__ bh1,
    float* __restrict__ t1, float* __restrict__ hstat1)
{
    const int gr = blockIdx.x;
    const int o = threadIdx.x;
    __shared__ float bn0[128];
    const float invG = 1.0f / (float)N_GRAPHS;
    for (int j = o; j < 128; j += 64) {
        float m = hstat0[j] * invG;
        float v = hstat0[128 + j] * invG - m * m;
        bn0[j] = (t0[gr * 128 + j] - m) * rsqrtf(v + EPS) * gh0[j] + beh0[j];
    }
    __syncthreads();
    float acc = bh1[o];
    for (int j = 0; j < 128; ++j) acc = fmaf(bn0[j], Wh1[j * 64 + o], acc);
    float y = sigmoidf_(acc);
    t1[gr * 64 + o] = y;
    atomicAdd(&hstat1[o], y);
    atomicAdd(&hstat1[64 + o], y * y);
}

__global__ __launch_bounds__(64) void head3_kernel(
    const float* __restrict__ t1, const float* __restrict__ hstat1,
    const float* __restrict__ gh1, const float* __restrict__ beh1,
    const float* __restrict__ Wc, const float* __restrict__ bc,
    float* __restrict__ out)
{
    const int gr = blockIdx.x;
    const int o = threadIdx.x;
    const float invG = 1.0f / (float)N_GRAPHS;
    float m = hstat1[o] * invG;
    float v = hstat1[64 + o] * invG - m * m;
    float b = (t1[gr * 64 + o] - m) * rsqrtf(v + EPS) * gh1[o] + beh1[o];
    float p0 = b * Wc[o * 2];
    float p1 = b * Wc[o * 2 + 1];
#pragma unroll
    for (int off = 32; off > 0; off >>= 1) {
        p0 += __shfl_down(p0, off);
        p1 += __shfl_down(p1, off);
    }
    if (o == 0) {
        out[gr * 2] = p0 + bc[0];
        out[gr * 2 + 1] = p1 + bc[1];
    }
}

// ---------------------------------------------------------------------------
extern "C" void kernel_launch(void* const* d_in, const int* in_sizes, int n_in,
                              void* d_out, int out_size, void* d_ws, size_t ws_size,
                              hipStream_t stream)
{
    const float* x     = (const float*)d_in[0];
    const int*   ei    = (const int*)d_in[1];
    const int*   batch = (const int*)d_in[2];
    const int N = in_sizes[2];
    const int E = in_sizes[1] / 2;
    const int NCHUNK = (N + 1023) / 1024;

    const float *Wk0 = (const float*)d_in[3],  *bk0 = (const float*)d_in[4];
    const float *Wq0 = (const float*)d_in[5],  *bq0 = (const float*)d_in[6];
    const float *Wv0 = (const float*)d_in[7],  *bv0 = (const float*)d_in[8];
    const float *Ws0 = (const float*)d_in[9],  *cb0 = (const float*)d_in[10];
    const float *g0  = (const float*)d_in[11], *be0 = (const float*)d_in[12];
    const float *Wk1 = (const float*)d_in[13], *bk1 = (const float*)d_in[14];
    const float *Wq1 = (const float*)d_in[15], *bq1 = (const float*)d_in[16];
    const float *Wv1 = (const float*)d_in[17], *bv1 = (const float*)d_in[18];
    const float *Ws1 = (const float*)d_in[19], *cb1 = (const float*)d_in[20];
    const float *g1  = (const float*)d_in[21], *be1 = (const float*)d_in[22];
    const float *Wh0 = (const float*)d_in[23], *bh0 = (const float*)d_in[24];
    const float *gh0 = (const float*)d_in[25], *beh0 = (const float*)d_in[26];
    const float *Wh1 = (const float*)d_in[27], *bh1 = (const float*)d_in[28];
    const float *gh1 = (const float*)d_in[29], *beh1 = (const float*)d_in[30];
    const float *Wc  = (const float*)d_in[31], *bc  = (const float*)d_in[32];

    float*    ws = (float*)d_ws;
    unsigned* KS = (unsigned*)ws;                      // N*64 packed fp16 k|s
    unsigned* QV = KS + (size_t)N * 64;                // N*64 packed fp16 q|v
    float*    H  = (float*)(QV + (size_t)N * 64);      // N*64 fp32 (raw y)
    int*   col     = (int*)(H + (size_t)N * 64);       // E
    int*   rowptr  = col + E;             // N+1
    int*   rp1loc  = rowptr + N + 1;      // N
    int*   cursor  = rp1loc + N;          // N (unused; kept for layout)
    int*   psum    = cursor + N;          // 256
    uintptr_t pAl = ((uintptr_t)(psum + 256) + 63) & ~(uintptr_t)63;
    short* BT0h = (short*)pAl;            // 256*128 bf16 hi
    short* BT0l = BT0h + 256 * 128;       // 256*128 bf16 lo
    float* bf0  = (float*)(BT0l + 256 * 128);  // 256
    short* BT1h = (short*)(bf0 + 256);    // 256*64 bf16 hi
    short* BT1l = BT1h + 256 * 64;        // 256*64 bf16 lo
    float* bf1  = (float*)(BT1l + 256 * 64);   // 256
    int*   deg     = (int*)(bf1 + 256);   // N    <-- zero zone starts here
    float* gsumy0 = (float*)(deg + N);    // 128*64
    float* gsumy1 = gsumy0 + 128 * 64;    // 128*64
    float* counts = gsumy1 + 128 * 64;    // 128
    float* stats0 = counts + 128;         // 128
    float* stats1 = stats0 + 128;         // 128
    float* hstat0 = stats1 + 128;         // 256
    float* hstat1 = hstat0 + 256;         // 128
    size_t zbytes = (size_t)N * sizeof(int) +
                    (size_t)(128 * 64 * 2 + 128 * 3 + 256 + 128) * sizeof(float);
    float* t0 = hstat1 + 128;             // 128*128
    float* t1 = t0 + 128 * 128;           // 128*64

    // pos_ aliases KS: lifetimes disjoint (pos_ dies at scatter, KS is born
    // at proj0). E ints (4 MB) <= N*64 uints (25.6 MB).
    int* pos_ = (int*)KS;

    hipMemsetAsync(deg, 0, zbytes, stream);

    // ---- fused prep (deg histogram + slot capture + counts + weights) ----
    prep_kernel<<<400, 256, 0, stream>>>(
        ei, deg, pos_, E, batch, counts, N,
        Wk0, bk0, Wq0, bq0, Wv0, bv0, Ws0, cb0, BT0h, BT0l, bf0,
        Wk1, bk1, Wq1, bq1, Wv1, bv1, Ws1, cb1, BT1h, BT1l, bf1);
    scan1_kernel<<<NCHUNK, 256, 0, stream>>>(deg, rp1loc, psum, N);
    scan2_kernel<<<1, 256, 0, stream>>>(psum, NCHUNK);
    scan3_kernel<<<256, 256, 0, stream>>>(rp1loc, psum, rowptr, N);
    scatter_kernel<<<512, 256, 0, stream>>>(ei, rowptr, pos_, col, E);

    const float invN = 1.0f / (float)N;
    const int projBlocks = (N + 63) / 64;

    // ---- layer 0 ----
    proj_mfma_kernel<128, false><<<projBlocks, 256, 0, stream>>>(
        x, BT0h, BT0l, bf0, nullptr, nullptr, nullptr, invN, KS, QV, N);
    agg_kernel<<<2048, 256, 0, stream>>>(rowptr, col, KS, QV, batch,
                                         H, stats0, gsumy0, N);

    // ---- layer 1 (BN affine computed in-kernel from stats0) ----
    proj_mfma_kernel<64, true><<<projBlocks, 256, 0, stream>>>(
        H, BT1h, BT1l, bf1, stats0, g0, be0, invN, KS, QV, N);
    agg_kernel<<<2048, 256, 0, stream>>>(rowptr, col, KS, QV, batch,
                                         H, stats1, gsumy1, N);

    // ---- head ----
    head1_kernel<<<128, 128, 0, stream>>>(gsumy0, gsumy1, counts,
                                          stats0, stats1, g0, be0, g1, be1,
                                          Wh0, bh0, t0, hstat0, invN);
    head2_kernel<<<128, 64, 0, stream>>>(t0, hstat0, gh0, beh0, Wh1, bh1, t1, hstat1);
    head3_kernel<<<128, 64, 0, stream>>>(t1, hstat1, gh1, beh1, Wc, bc, (float*)d_out);
}